// Round 11
// baseline (151.145 us; speedup 1.0000x reference)
//
#include <hip/hip_runtime.h>

#define NPTS   25600
#define NB     16
#define NRES   320
#define OS     400
#define NCELL  (OS * OS)      // 160000
#define CAP    16
#define MAXOVF 4096

#define NJA    8              // lines per pass-A block
#define NJB    5              // lines per pass-B block (64*16 = 1024 blocks = exactly 4/CU)
#define FFTTH  512            // threads per FFT block
#define LSTRV  404            // LDS line stride in float2

// BETA = pi * sqrt((4/1.25*0.75)^2 - 0.8) = pi*sqrt(4.96)
#define BETA_F (3.14159265358979f * 2.22710574513201f)

__device__ __forceinline__ float bessel_i0f(float x) {
    float ax = fabsf(x);
    if (ax < 3.75f) {
        float t = (ax * ax) * (1.0f / 14.0625f);
        return 1.0f + t * (3.5156229f + t * (3.0899424f + t * (1.2067492f +
                     t * (0.2659732f + t * (0.0360768f + t * 0.0045813f)))));
    } else {
        float t = 3.75f / ax;
        return (expf(ax) * rsqrtf(ax)) *
               (0.39894228f + t * (0.01328592f + t * (0.00225319f + t * (-0.00157565f +
                t * (0.00916281f + t * (-0.02057706f + t * (0.02635537f +
                t * (-0.01647633f + t * 0.00392377f))))))));
    }
}

struct OvfEntry { int cell; int m; float w; float pad; };

// ---------------------------------------------------------------------------
// Fused: blocks [0,1600) bilinear-sample -> val[m][b]; blocks [1600,1700)
// compute KB taps -> slot-major ELL bins (cell = i1*OS + i0, j-major).
// ---------------------------------------------------------------------------
__global__ __launch_bounds__(256)
void k_sample_taps(const float* __restrict__ ksp,
                   const float* __restrict__ traj,
                   float2* __restrict__ val,
                   int* __restrict__ cursor,
                   float2* __restrict__ entries,
                   int* __restrict__ ovf_cnt,
                   OvfEntry* __restrict__ ovf)
{
    int blk = blockIdx.x;
    if (blk < 1600) {
        int gid = blk * 256 + threadIdx.x;
        int b = gid & 15;
        int m = gid >> 4;

        float tx = traj[2 * m + 0];
        float ty = traj[2 * m + 1];

        float px = (tx * (1.0f / 160.0f) + 1.0f) * 0.5f * 319.0f;
        float py = (ty * (1.0f / 160.0f) + 1.0f) * 0.5f * 319.0f;
        float fx0 = floorf(px), fy0 = floorf(py);
        int x0 = (int)fx0, y0 = (int)fy0;
        float wx1 = px - fx0, wy1 = py - fy0;
        float wx0 = 1.0f - wx1, wy0 = 1.0f - wy1;
        x0 = min(max(x0, 0), NRES - 1);
        y0 = min(max(y0, 0), NRES - 1);
        int x1 = min(x0 + 1, NRES - 1);
        int y1 = min(y0 + 1, NRES - 1);

        const float2* base = (const float2*)ksp + (size_t)b * NRES * NRES;
        float2 v00 = base[y0 * NRES + x0];
        float2 v01 = base[y0 * NRES + x1];
        float2 v10 = base[y1 * NRES + x0];
        float2 v11 = base[y1 * NRES + x1];
        float sr = (v00.x * wx0 + v01.x * wx1) * wy0 + (v10.x * wx0 + v11.x * wx1) * wy1;
        float si = (v00.y * wx0 + v01.y * wx1) * wy0 + (v10.y * wx0 + v11.y * wx1) * wy1;

        val[gid] = make_float2(sr, si);
    } else {
        int m = (blk - 1600) * 256 + threadIdx.x;
        if (m >= NPTS) return;

        float tx = traj[2 * m + 0];
        float ty = traj[2 * m + 1];
        float c0 = tx * 1.25f + 200.0f;
        float c1 = ty * 1.25f + 200.0f;
        float s0 = ceilf(c0 - 2.0f);
        float s1 = ceilf(c1 - 2.0f);

        float w0[4], w1[4];
        int   i0[4], i1[4];
#pragma unroll
        for (int t = 0; t < 4; t++) {
            float id0 = s0 + (float)t;
            float d0 = (c0 - id0) * 0.5f;
            float t0 = fmaxf(1.0f - d0 * d0, 0.0f);
            w0[t] = bessel_i0f(BETA_F * sqrtf(t0)) * 0.25f;
            i0[t] = (((int)id0) + OS) % OS;

            float id1 = s1 + (float)t;
            float d1 = (c1 - id1) * 0.5f;
            float t1 = fmaxf(1.0f - d1 * d1, 0.0f);
            w1[t] = bessel_i0f(BETA_F * sqrtf(t1)) * 0.25f;
            i1[t] = (((int)id1) + OS) % OS;
        }

#pragma unroll
        for (int t0 = 0; t0 < 4; t0++) {
#pragma unroll
            for (int t1 = 0; t1 < 4; t1++) {
                int cell = i1[t1] * OS + i0[t0];
                float w = w0[t0] * w1[t1];
                int slot = atomicAdd(&cursor[cell], 1);
                if (slot < CAP) {
                    entries[(size_t)slot * NCELL + cell] = make_float2(__int_as_float(m), w);
                } else {
                    int oi = atomicAdd(ovf_cnt, 1);
                    if (oi < MAXOVF) { ovf[oi].cell = cell; ovf[oi].m = m; ovf[oi].w = w; }
                }
            }
        }
    }
}

// ---------------------------------------------------------------------------
// Gather-SpMM: one thread per cell, all 16 batches in float4 registers.
// ---------------------------------------------------------------------------
__global__ __launch_bounds__(256)
void k_gather(const int* __restrict__ cursor,
              const float2* __restrict__ entries,
              const float4* __restrict__ val4,   // (25600, 8 float4)
              float2* __restrict__ grid,
              const int* __restrict__ ovf_cnt,
              const OvfEntry* __restrict__ ovf)
{
    int cell = blockIdx.x * blockDim.x + threadIdx.x;
    if (cell >= NCELL) return;
    int cnt_raw = cursor[cell];
    int cnt = min(cnt_raw, CAP);

    float4 acc[8];
#pragma unroll
    for (int q = 0; q < 8; q++) acc[q] = make_float4(0.f, 0.f, 0.f, 0.f);

    for (int k = 0; k < cnt; k++) {
        float2 e = entries[(size_t)k * NCELL + cell];
        int m = __float_as_int(e.x);
        float w = e.y;
        const float4* v = val4 + (size_t)m * 8;
#pragma unroll
        for (int q = 0; q < 8; q++) {
            float4 x = v[q];
            acc[q].x = fmaf(w, x.x, acc[q].x);
            acc[q].y = fmaf(w, x.y, acc[q].y);
            acc[q].z = fmaf(w, x.z, acc[q].z);
            acc[q].w = fmaf(w, x.w, acc[q].w);
        }
    }

    if (cnt_raw > CAP) {
        int n = min(*ovf_cnt, MAXOVF);
        for (int i = 0; i < n; i++) {
            if (ovf[i].cell != cell) continue;
            int m = ovf[i].m;
            float w = ovf[i].w;
            const float4* v = val4 + (size_t)m * 8;
#pragma unroll
            for (int q = 0; q < 8; q++) {
                float4 x = v[q];
                acc[q].x = fmaf(w, x.x, acc[q].x);
                acc[q].y = fmaf(w, x.y, acc[q].y);
                acc[q].z = fmaf(w, x.z, acc[q].z);
                acc[q].w = fmaf(w, x.w, acc[q].w);
            }
        }
    }

#pragma unroll
    for (int q = 0; q < 8; q++) {
        grid[(size_t)(2 * q + 0) * NCELL + cell] = make_float2(acc[q].x, acc[q].y);
        grid[(size_t)(2 * q + 1) * NCELL + cell] = make_float2(acc[q].z, acc[q].w);
    }
}

// ---------------------------------------------------------------------------
// 20-pt conjugate-pair sub-DFT with pairing folded in (see R10 notes).
// ---------------------------------------------------------------------------
__device__ __forceinline__ void dft20_conj(const float2* __restrict__ Al, int off, int kh,
                                           const float2* __restrict__ E20t,
                                           float& y1r, float& y1i, float& y2r, float& y2i)
{
    float2 x0 = Al[off], x10 = Al[off + 200];
    if (kh == 0) {
        float br = x0.x + x10.x, bi = x0.y + x10.y;
        float ar = 0.f, ai = 0.f, dr = 0.f, di = 0.f;
#pragma unroll
        for (int j = 1; j <= 9; j++) {
            float2 xa = Al[off + 20 * j];
            float2 xb = Al[off + 400 - 20 * j];
            float pr = xa.x + xb.x, pi = xa.y + xb.y;
            ar += pr; ai += pi;
            float sg = (j & 1) ? -1.f : 1.f;
            dr = fmaf(sg, pr, dr); di = fmaf(sg, pi, di);
        }
        y1r = br + ar; y1i = bi + ai;     // k = 0
        y2r = br + dr; y2i = bi + di;     // k = 10
    } else {
        float sgn = (kh & 1) ? -1.f : 1.f;
        float br = fmaf(sgn, x10.x, x0.x), bi = fmaf(sgn, x10.y, x0.y);
        float2 ek = E20t[kh];
        float c = ek.x, s = ek.y;
        float Asr = 0.f, Asi = 0.f, Bsr = 0.f, Bsi = 0.f;
#pragma unroll
        for (int j = 1; j <= 9; j++) {
            float2 xa = Al[off + 20 * j];
            float2 xb = Al[off + 400 - 20 * j];
            float pr = xa.x + xb.x, pi = xa.y + xb.y;   // xp
            float mr = xa.x - xb.x, mi = xa.y - xb.y;   // xm
            Asr = fmaf(c, pr, Asr); Asi = fmaf(c, pi, Asi);
            Bsr = fmaf(s, mi, Bsr); Bsi = fmaf(s, mr, Bsi);
            float cn = c * ek.x - s * ek.y;
            s = c * ek.y + s * ek.x;
            c = cn;
        }
        y1r = br + Asr - Bsr; y1i = bi + Asi + Bsi;     // k = kh
        y2r = br + Asr + Bsr; y2i = bi + Asi - Bsi;     // k = 20-kh
    }
}

__device__ __forceinline__ float apodf(int i) {
    float t = (float)(i - 160) * 0.031415926535897932f;  // pi*4/400
    float a = sqrtf(fmaxf(BETA_F * BETA_F - t * t, 1e-12f));
    return a / sinhf(a);
}

// Pass A: lines = grid rows (fixed j=i1), transform i0 axis -> At[b][uc][j].
// 512 threads / 8 lines: 800 blocks, <=4/CU, single scheduling round.
__global__ __launch_bounds__(FFTTH, 4)
void k_fft_pass_a(const float* __restrict__ grid, float* __restrict__ At)
{
    __shared__ __align__(16) float2 A[NJA * LSTRV];
    __shared__ float2 E20t[20];
    __shared__ float2 E400p[424];     // swizzled: entry t at t + (t>>4)
    int tid = threadIdx.x;
    int b = blockIdx.y;
    int j0 = blockIdx.x * NJA;

    if (tid < 400) {
        float sn, cs;
        sincosf((float)tid * 0.015707963267948966f, &sn, &cs);   // 2*pi/400
        E400p[tid + (tid >> 4)] = make_float2(cs, sn);
    } else if (tid >= 448 && tid < 468) {
        int t = tid - 448;
        float sn, cs;
        sincosf((float)t * 0.3141592653589793f, &sn, &cs);       // 2*pi/20
        E20t[t] = make_float2(cs, sn);
    }

    // staging: 8 contiguous lines = 1600 float4
    const float4* g4 = (const float4*)(grid + ((size_t)b * NCELL + (size_t)j0 * OS) * 2);
    float4* A4 = (float4*)A;
    for (int o = tid; o < NJA * 200; o += FFTTH) {
        int r = o / 200, q = o - r * 200;
        A4[r * (LSTRV / 2) + q] = g4[o];
    }
    __syncthreads();

    // ---- stage 1: items = NJA*200 = 1600, <=4 per thread, reg-held ----
    float v1r[4], v1i[4], v2r[4], v2i[4];
#pragma unroll
    for (int it = 0; it < 4; it++) {
        int o = tid + it * FFTTH;
        if (o < NJA * 200) {
            int r = o / 200, q = o - r * 200;
            int kh = q / 20, n2 = q - kh * 20;
            float y1r, y1i, y2r, y2i;
            dft20_conj(&A[r * LSTRV], n2, kh, E20t, y1r, y1i, y2r, y2i);
            if (kh == 0) {
                v1r[it] = y1r; v1i[it] = y1i;
                int ti = 10 * n2;
                float2 tw = E400p[ti + (ti >> 4)];
                v2r[it] = y2r * tw.x - y2i * tw.y; v2i[it] = y2r * tw.y + y2i * tw.x;
            } else {
                int t1 = n2 * kh, t2 = n2 * (20 - kh);
                float2 w1 = E400p[t1 + (t1 >> 4)], w2 = E400p[t2 + (t2 >> 4)];
                v1r[it] = y1r * w1.x - y1i * w1.y; v1i[it] = y1r * w1.y + y1i * w1.x;
                v2r[it] = y2r * w2.x - y2i * w2.y; v2i[it] = y2r * w2.y + y2i * w2.x;
            }
        }
    }
    __syncthreads();
#pragma unroll
    for (int it = 0; it < 4; it++) {
        int o = tid + it * FFTTH;
        if (o < NJA * 200) {
            int r = o / 200, q = o - r * 200;
            int kh = q / 20, n2 = q - kh * 20;
            float2* Al = &A[r * LSTRV + 20 * n2];
            if (kh == 0) {
                Al[0]  = make_float2(v1r[it], v1i[it]);
                Al[10] = make_float2(v2r[it], v2i[it]);
            } else {
                Al[kh]      = make_float2(v1r[it], v1i[it]);
                Al[20 - kh] = make_float2(v2r[it], v2i[it]);
            }
        }
    }
    __syncthreads();

    // ---- stage 2 (crop): items = NJA*180 = 1440, <=3 per thread ----
#pragma unroll
    for (int it = 0; it < 3; it++) {
        int o = tid + it * FFTTH;
        if (o < NJA * 180) {
            int r = o / 180, q = o - r * 180;
            int k2h = q / 20, k1 = q - k2h * 20;
            float y1r, y1i, y2r, y2i;
            dft20_conj(&A[r * LSTRV], k1, k2h, E20t, y1r, y1i, y2r, y2i);
            v1r[it] = y1r; v1i[it] = y1i;
            v2r[it] = y2r; v2i[it] = y2i;
        }
    }
    __syncthreads();
#pragma unroll
    for (int it = 0; it < 3; it++) {
        int o = tid + it * FFTTH;
        if (o < NJA * 180) {
            int r = o / 180, q = o - r * 180;
            int k2h = q / 20, k1 = q - k2h * 20;
            float2* Al = &A[r * LSTRV];
            if (k2h == 0) {
                Al[k1] = make_float2(v1r[it], v1i[it]);                  // k2=0
            } else {
                if (k2h <= 7)
                    Al[20 * k2h + k1] = make_float2(v1r[it], v1i[it]);   // k2=k2h
                Al[320 - 20 * k2h + k1] = make_float2(v2r[it], v2i[it]); // k2=20-k2h
            }
        }
    }
    __syncthreads();

    // transposed store: At[b][uc][j0+r], 64 B segments per uc
    float2* At2 = (float2*)At;
    for (int o = tid; o < 320 * NJA; o += FFTTH) {
        int uc = o >> 3, r = o & 7;
        At2[((size_t)b * 320 + uc) * OS + j0 + r] = A[r * LSTRV + uc];
    }
}

// Pass B: lines = At rows (fixed uc), transform j axis; stage 2 streams the
// fused crop/shift/apod epilogue straight to global. NJB=5 -> 1024 blocks
// = exactly 4 blocks/CU, one full scheduling round.
__global__ __launch_bounds__(FFTTH, 4)
void k_fft_pass_b(const float* __restrict__ At, float* __restrict__ out)
{
    __shared__ __align__(16) float2 A[NJB * LSTRV];
    __shared__ float2 E20t[20];
    __shared__ float2 E400p[424];
    __shared__ float apodT[320];
    int tid = threadIdx.x;
    int b = blockIdx.y;
    int uc0 = blockIdx.x * NJB;

    if (tid < 400) {
        float sn, cs;
        sincosf((float)tid * 0.015707963267948966f, &sn, &cs);
        E400p[tid + (tid >> 4)] = make_float2(cs, sn);
    } else if (tid >= 448 && tid < 468) {
        int t = tid - 448;
        float sn, cs;
        sincosf((float)t * 0.3141592653589793f, &sn, &cs);
        E20t[t] = make_float2(cs, sn);
    }
    if (tid < 320) apodT[tid] = apodf(tid);

    const float4* a4 = (const float4*)(At + ((size_t)b * 320 + uc0) * OS * 2);
    float4* A4 = (float4*)A;
    for (int o = tid; o < NJB * 200; o += FFTTH) {
        int r = o / 200, q = o - r * 200;
        A4[r * (LSTRV / 2) + q] = a4[o];
    }
    __syncthreads();

    // ---- stage 1: items = NJB*200 = 1000, <=2 per thread ----
    float v1r[2], v1i[2], v2r[2], v2i[2];
#pragma unroll
    for (int it = 0; it < 2; it++) {
        int o = tid + it * FFTTH;
        if (o < NJB * 200) {
            int r = o / 200, q = o - r * 200;
            int kh = q / 20, n2 = q - kh * 20;
            float y1r, y1i, y2r, y2i;
            dft20_conj(&A[r * LSTRV], n2, kh, E20t, y1r, y1i, y2r, y2i);
            if (kh == 0) {
                v1r[it] = y1r; v1i[it] = y1i;
                int ti = 10 * n2;
                float2 tw = E400p[ti + (ti >> 4)];
                v2r[it] = y2r * tw.x - y2i * tw.y; v2i[it] = y2r * tw.y + y2i * tw.x;
            } else {
                int t1 = n2 * kh, t2 = n2 * (20 - kh);
                float2 w1 = E400p[t1 + (t1 >> 4)], w2 = E400p[t2 + (t2 >> 4)];
                v1r[it] = y1r * w1.x - y1i * w1.y; v1i[it] = y1r * w1.y + y1i * w1.x;
                v2r[it] = y2r * w2.x - y2i * w2.y; v2i[it] = y2r * w2.y + y2i * w2.x;
            }
        }
    }
    __syncthreads();
#pragma unroll
    for (int it = 0; it < 2; it++) {
        int o = tid + it * FFTTH;
        if (o < NJB * 200) {
            int r = o / 200, q = o - r * 200;
            int kh = q / 20, n2 = q - kh * 20;
            float2* Al = &A[r * LSTRV + 20 * n2];
            if (kh == 0) {
                Al[0]  = make_float2(v1r[it], v1i[it]);
                Al[10] = make_float2(v2r[it], v2i[it]);
            } else {
                Al[kh]      = make_float2(v1r[it], v1i[it]);
                Al[20 - kh] = make_float2(v2r[it], v2i[it]);
            }
        }
    }
    __syncthreads();

    // ---- stage 2 + fused epilogue -> global: items = NJB*180 = 900 ----
    for (int o = tid; o < NJB * 180; o += FFTTH) {
        int r = o / 180, q = o - r * 180;
        int k2h = q / 20, k1 = q - k2h * 20;
        float y1r, y1i, y2r, y2i;
        dft20_conj(&A[r * LSTRV], k1, k2h, E20t, y1r, y1i, y2r, y2i);

        int y = uc0 + r + 160; if (y >= 320) y -= 320;
        float apy = (1.0f / 320.0f) * apodT[y];
        float* o0 = out + (((size_t)b * 2 + 0) * NRES + y) * NRES;
        float* o1 = out + (((size_t)b * 2 + 1) * NRES + y) * NRES;

        if (k2h <= 7) {                                  // k2 = k2h (incl. 0)
            int vc = 20 * k2h + k1;
            int x = vc + 160; if (x >= 320) x -= 320;
            float sg = ((x + y) & 1) ? -1.0f : 1.0f;
            float sc = sg * apy * apodT[x];
            o0[x] = y1r * sc;
            o1[x] = y1i * sc;
        }
        if (k2h >= 1) {                                  // k2 = 20-k2h
            int vc = 320 - 20 * k2h + k1;
            int x = vc + 160; if (x >= 320) x -= 320;
            float sg = ((x + y) & 1) ? -1.0f : 1.0f;
            float sc = sg * apy * apodT[x];
            o0[x] = y2r * sc;
            o1[x] = y2i * sc;
        }
    }
}

extern "C" void kernel_launch(void* const* d_in, const int* in_sizes, int n_in,
                              void* d_out, int out_size, void* d_ws, size_t ws_size,
                              hipStream_t stream) {
    const float* ksp  = (const float*)d_in[0];
    const float* traj = (const float*)d_in[1];
    float* out = (float*)d_out;

    // ws layout (floats):
    //   grid    : NB*NCELL*2 = 5,120,000 (20.48 MB)
    //   At      : NB*320*OS*2 = 4,096,000 (16.38 MB)
    //   entries : CAP*NCELL float2 (20.48 MB)
    //   val     : NPTS*NB float2 (3.28 MB)
    //   cursor  : NCELL ints; ovf_cnt; ovf
    float* grid = (float*)d_ws;
    float* At   = grid + (size_t)NB * NCELL * 2;
    float2* entries = (float2*)(At + (size_t)NB * 320 * OS * 2);
    float2* val = (float2*)(entries + (size_t)CAP * NCELL);
    int* cursor  = (int*)(val + (size_t)NPTS * NB);
    int* ovf_cnt = cursor + NCELL;
    OvfEntry* ovf = (OvfEntry*)(ovf_cnt + 16);

    hipMemsetAsync(cursor, 0, (NCELL + 16) * sizeof(int), stream);

    k_sample_taps<<<dim3(1700), 256, 0, stream>>>(ksp, traj, val, cursor, entries, ovf_cnt, ovf);
    k_gather     <<<dim3((NCELL + 255) / 256), 256, 0, stream>>>(cursor, entries, (const float4*)val,
                                                                 (float2*)grid, ovf_cnt, ovf);
    k_fft_pass_a <<<dim3(OS / NJA, NB),  FFTTH, 0, stream>>>(grid, At);
    k_fft_pass_b <<<dim3(320 / NJB, NB), FFTTH, 0, stream>>>(At, out);
}

// Round 12
// 147.359 us; speedup vs baseline: 1.0257x; 1.0257x over previous
//
#include <hip/hip_runtime.h>

#define NPTS   25600
#define NB     16
#define NRES   320
#define OS     400
#define NCELL  (OS * OS)      // 160000
#define CAP    16
#define MAXOVF 4096

#define NJA    8              // lines per pass-A block
#define NJB    5              // lines per pass-B block
#define FFTTH  512            // threads per FFT block
#define LSTRV  404            // LDS line stride in float2

// BETA = pi * sqrt((4/1.25*0.75)^2 - 0.8) = pi*sqrt(4.96)
#define BETA_F (3.14159265358979f * 2.22710574513201f)

__device__ __forceinline__ float bessel_i0f(float x) {
    float ax = fabsf(x);
    if (ax < 3.75f) {
        float t = (ax * ax) * (1.0f / 14.0625f);
        return 1.0f + t * (3.5156229f + t * (3.0899424f + t * (1.2067492f +
                     t * (0.2659732f + t * (0.0360768f + t * 0.0045813f)))));
    } else {
        float t = 3.75f / ax;
        return (expf(ax) * rsqrtf(ax)) *
               (0.39894228f + t * (0.01328592f + t * (0.00225319f + t * (-0.00157565f +
                t * (0.00916281f + t * (-0.02057706f + t * (0.02635537f +
                t * (-0.01647633f + t * 0.00392377f))))))));
    }
}

struct OvfEntry { int cell; int m; float w; float pad; };

// ---------------------------------------------------------------------------
// Transpose ksp (b,y,x) -> kspT (y,x,b) so the sampler's random-point reads
// become 128 B coalesced rows. Also zeroes cursor/ovf_cnt (absorbs memset).
// Tile: 8y x 8x x 16b = 1024 threads, LDS-padded.
// ---------------------------------------------------------------------------
__global__ __launch_bounds__(1024)
void k_transpose(const float2* __restrict__ ksp, float2* __restrict__ kspT,
                 int* __restrict__ cursor, int* __restrict__ ovf_cnt)
{
    __shared__ float2 T[8 * 8 * 17];
    int tid = threadIdx.x;
    int bx = blockIdx.x % 40, by = blockIdx.x / 40;
    int x0 = bx * 8, y0 = by * 8;

    // zero cursor: 1600 blocks x 100 ints = 160000 exactly
    int cbase = blockIdx.x * 100;
    if (tid < 100) cursor[cbase + tid] = 0;
    if (blockIdx.x == 0 && tid >= 100 && tid < 116) ovf_cnt[tid - 100] = 0;

    // read: coalesced 64 B per (b, y-row)
    int b  = tid >> 6, yl = (tid >> 3) & 7, xl = tid & 7;
    T[(yl * 8 + xl) * 17 + b] = ksp[((size_t)b * NRES + (y0 + yl)) * NRES + x0 + xl];
    __syncthreads();

    // write: b inner -> 1 KB contiguous per (y, 8x) group
    int yl2 = tid >> 7, xl2 = (tid >> 4) & 7, b2 = tid & 15;
    kspT[((size_t)(y0 + yl2) * NRES + x0 + xl2) * NB + b2] = T[(yl2 * 8 + xl2) * 17 + b2];
}

// ---------------------------------------------------------------------------
// Fused: blocks [0,1600) bilinear-sample from kspT -> val[m][b] (coalesced
// 128 B row reads); blocks [1600,1700) KB taps -> slot-major ELL bins.
// ---------------------------------------------------------------------------
__global__ __launch_bounds__(256)
void k_sample_taps(const float2* __restrict__ kspT,
                   const float* __restrict__ traj,
                   float2* __restrict__ val,
                   int* __restrict__ cursor,
                   float2* __restrict__ entries,
                   int* __restrict__ ovf_cnt,
                   OvfEntry* __restrict__ ovf)
{
    int blk = blockIdx.x;
    if (blk < 1600) {
        int gid = blk * 256 + threadIdx.x;
        int b = gid & 15;
        int m = gid >> 4;

        float tx = traj[2 * m + 0];
        float ty = traj[2 * m + 1];

        // px,py in [0,319): x0<=318, y0<=318 -> no clamping needed
        float px = (tx * (1.0f / 160.0f) + 1.0f) * 0.5f * 319.0f;
        float py = (ty * (1.0f / 160.0f) + 1.0f) * 0.5f * 319.0f;
        float fx0 = floorf(px), fy0 = floorf(py);
        int x0 = (int)fx0, y0 = (int)fy0;
        float wx1 = px - fx0, wy1 = py - fy0;
        float wx0 = 1.0f - wx1, wy0 = 1.0f - wy1;

        const float2* row0 = kspT + ((size_t)y0 * NRES + x0) * NB + b;
        const float2* row1 = row0 + (size_t)NRES * NB;
        float2 v00 = row0[0];
        float2 v01 = row0[NB];
        float2 v10 = row1[0];
        float2 v11 = row1[NB];
        float sr = (v00.x * wx0 + v01.x * wx1) * wy0 + (v10.x * wx0 + v11.x * wx1) * wy1;
        float si = (v00.y * wx0 + v01.y * wx1) * wy0 + (v10.y * wx0 + v11.y * wx1) * wy1;

        val[gid] = make_float2(sr, si);
    } else {
        int m = (blk - 1600) * 256 + threadIdx.x;
        if (m >= NPTS) return;

        float tx = traj[2 * m + 0];
        float ty = traj[2 * m + 1];
        float c0 = tx * 1.25f + 200.0f;
        float c1 = ty * 1.25f + 200.0f;
        float s0 = ceilf(c0 - 2.0f);
        float s1 = ceilf(c1 - 2.0f);

        float w0[4], w1[4];
        int   i0[4], i1[4];
#pragma unroll
        for (int t = 0; t < 4; t++) {
            float id0 = s0 + (float)t;
            float d0 = (c0 - id0) * 0.5f;
            float t0 = fmaxf(1.0f - d0 * d0, 0.0f);
            w0[t] = bessel_i0f(BETA_F * sqrtf(t0)) * 0.25f;
            i0[t] = (((int)id0) + OS) % OS;

            float id1 = s1 + (float)t;
            float d1 = (c1 - id1) * 0.5f;
            float t1 = fmaxf(1.0f - d1 * d1, 0.0f);
            w1[t] = bessel_i0f(BETA_F * sqrtf(t1)) * 0.25f;
            i1[t] = (((int)id1) + OS) % OS;
        }

#pragma unroll
        for (int t0 = 0; t0 < 4; t0++) {
#pragma unroll
            for (int t1 = 0; t1 < 4; t1++) {
                int cell = i1[t1] * OS + i0[t0];
                float w = w0[t0] * w1[t1];
                int slot = atomicAdd(&cursor[cell], 1);
                if (slot < CAP) {
                    entries[(size_t)slot * NCELL + cell] = make_float2(__int_as_float(m), w);
                } else {
                    int oi = atomicAdd(ovf_cnt, 1);
                    if (oi < MAXOVF) { ovf[oi].cell = cell; ovf[oi].m = m; ovf[oi].w = w; }
                }
            }
        }
    }
}

// ---------------------------------------------------------------------------
// Gather-SpMM: one thread per cell, all 16 batches in float4 registers.
// ---------------------------------------------------------------------------
__global__ __launch_bounds__(256)
void k_gather(const int* __restrict__ cursor,
              const float2* __restrict__ entries,
              const float4* __restrict__ val4,   // (25600, 8 float4)
              float2* __restrict__ grid,
              const int* __restrict__ ovf_cnt,
              const OvfEntry* __restrict__ ovf)
{
    int cell = blockIdx.x * blockDim.x + threadIdx.x;
    if (cell >= NCELL) return;
    int cnt_raw = cursor[cell];
    int cnt = min(cnt_raw, CAP);

    float4 acc[8];
#pragma unroll
    for (int q = 0; q < 8; q++) acc[q] = make_float4(0.f, 0.f, 0.f, 0.f);

    for (int k = 0; k < cnt; k++) {
        float2 e = entries[(size_t)k * NCELL + cell];
        int m = __float_as_int(e.x);
        float w = e.y;
        const float4* v = val4 + (size_t)m * 8;
#pragma unroll
        for (int q = 0; q < 8; q++) {
            float4 x = v[q];
            acc[q].x = fmaf(w, x.x, acc[q].x);
            acc[q].y = fmaf(w, x.y, acc[q].y);
            acc[q].z = fmaf(w, x.z, acc[q].z);
            acc[q].w = fmaf(w, x.w, acc[q].w);
        }
    }

    if (cnt_raw > CAP) {
        int n = min(*ovf_cnt, MAXOVF);
        for (int i = 0; i < n; i++) {
            if (ovf[i].cell != cell) continue;
            int m = ovf[i].m;
            float w = ovf[i].w;
            const float4* v = val4 + (size_t)m * 8;
#pragma unroll
            for (int q = 0; q < 8; q++) {
                float4 x = v[q];
                acc[q].x = fmaf(w, x.x, acc[q].x);
                acc[q].y = fmaf(w, x.y, acc[q].y);
                acc[q].z = fmaf(w, x.z, acc[q].z);
                acc[q].w = fmaf(w, x.w, acc[q].w);
            }
        }
    }

#pragma unroll
    for (int q = 0; q < 8; q++) {
        grid[(size_t)(2 * q + 0) * NCELL + cell] = make_float2(acc[q].x, acc[q].y);
        grid[(size_t)(2 * q + 1) * NCELL + cell] = make_float2(acc[q].z, acc[q].w);
    }
}

// ---------------------------------------------------------------------------
// 20-pt conjugate-pair sub-DFT with pairing folded in.
// ---------------------------------------------------------------------------
__device__ __forceinline__ void dft20_conj(const float2* __restrict__ Al, int off, int kh,
                                           const float2* __restrict__ E20t,
                                           float& y1r, float& y1i, float& y2r, float& y2i)
{
    float2 x0 = Al[off], x10 = Al[off + 200];
    if (kh == 0) {
        float br = x0.x + x10.x, bi = x0.y + x10.y;
        float ar = 0.f, ai = 0.f, dr = 0.f, di = 0.f;
#pragma unroll
        for (int j = 1; j <= 9; j++) {
            float2 xa = Al[off + 20 * j];
            float2 xb = Al[off + 400 - 20 * j];
            float pr = xa.x + xb.x, pi = xa.y + xb.y;
            ar += pr; ai += pi;
            float sg = (j & 1) ? -1.f : 1.f;
            dr = fmaf(sg, pr, dr); di = fmaf(sg, pi, di);
        }
        y1r = br + ar; y1i = bi + ai;     // k = 0
        y2r = br + dr; y2i = bi + di;     // k = 10
    } else {
        float sgn = (kh & 1) ? -1.f : 1.f;
        float br = fmaf(sgn, x10.x, x0.x), bi = fmaf(sgn, x10.y, x0.y);
        float2 ek = E20t[kh];
        float c = ek.x, s = ek.y;
        float Asr = 0.f, Asi = 0.f, Bsr = 0.f, Bsi = 0.f;
#pragma unroll
        for (int j = 1; j <= 9; j++) {
            float2 xa = Al[off + 20 * j];
            float2 xb = Al[off + 400 - 20 * j];
            float pr = xa.x + xb.x, pi = xa.y + xb.y;   // xp
            float mr = xa.x - xb.x, mi = xa.y - xb.y;   // xm
            Asr = fmaf(c, pr, Asr); Asi = fmaf(c, pi, Asi);
            Bsr = fmaf(s, mi, Bsr); Bsi = fmaf(s, mr, Bsi);
            float cn = c * ek.x - s * ek.y;
            s = c * ek.y + s * ek.x;
            c = cn;
        }
        y1r = br + Asr - Bsr; y1i = bi + Asi + Bsi;     // k = kh
        y2r = br + Asr + Bsr; y2i = bi + Asi - Bsi;     // k = 20-kh
    }
}

__device__ __forceinline__ float apodf(int i) {
    float t = (float)(i - 160) * 0.031415926535897932f;  // pi*4/400
    float a = sqrtf(fmaxf(BETA_F * BETA_F - t * t, 1e-12f));
    return a / sinhf(a);
}

// Pass A: lines = grid rows (fixed j=i1), transform i0 axis -> At[b][uc][j].
__global__ __launch_bounds__(FFTTH, 4)
void k_fft_pass_a(const float* __restrict__ grid, float* __restrict__ At)
{
    __shared__ __align__(16) float2 A[NJA * LSTRV];
    __shared__ float2 E20t[20];
    __shared__ float2 E400p[424];     // swizzled: entry t at t + (t>>4)
    int tid = threadIdx.x;
    int b = blockIdx.y;
    int j0 = blockIdx.x * NJA;

    if (tid < 400) {
        float sn, cs;
        sincosf((float)tid * 0.015707963267948966f, &sn, &cs);   // 2*pi/400
        E400p[tid + (tid >> 4)] = make_float2(cs, sn);
    } else if (tid >= 448 && tid < 468) {
        int t = tid - 448;
        float sn, cs;
        sincosf((float)t * 0.3141592653589793f, &sn, &cs);       // 2*pi/20
        E20t[t] = make_float2(cs, sn);
    }

    const float4* g4 = (const float4*)(grid + ((size_t)b * NCELL + (size_t)j0 * OS) * 2);
    float4* A4 = (float4*)A;
    for (int o = tid; o < NJA * 200; o += FFTTH) {
        int r = o / 200, q = o - r * 200;
        A4[r * (LSTRV / 2) + q] = g4[o];
    }
    __syncthreads();

    // ---- stage 1: items = 1600, <=4/thread, reg-held ----
    float v1r[4], v1i[4], v2r[4], v2i[4];
#pragma unroll
    for (int it = 0; it < 4; it++) {
        int o = tid + it * FFTTH;
        if (o < NJA * 200) {
            int r = o / 200, q = o - r * 200;
            int kh = q / 20, n2 = q - kh * 20;
            float y1r, y1i, y2r, y2i;
            dft20_conj(&A[r * LSTRV], n2, kh, E20t, y1r, y1i, y2r, y2i);
            if (kh == 0) {
                v1r[it] = y1r; v1i[it] = y1i;
                int ti = 10 * n2;
                float2 tw = E400p[ti + (ti >> 4)];
                v2r[it] = y2r * tw.x - y2i * tw.y; v2i[it] = y2r * tw.y + y2i * tw.x;
            } else {
                int t1 = n2 * kh, t2 = n2 * (20 - kh);
                float2 w1 = E400p[t1 + (t1 >> 4)], w2 = E400p[t2 + (t2 >> 4)];
                v1r[it] = y1r * w1.x - y1i * w1.y; v1i[it] = y1r * w1.y + y1i * w1.x;
                v2r[it] = y2r * w2.x - y2i * w2.y; v2i[it] = y2r * w2.y + y2i * w2.x;
            }
        }
    }
    __syncthreads();
#pragma unroll
    for (int it = 0; it < 4; it++) {
        int o = tid + it * FFTTH;
        if (o < NJA * 200) {
            int r = o / 200, q = o - r * 200;
            int kh = q / 20, n2 = q - kh * 20;
            float2* Al = &A[r * LSTRV + 20 * n2];
            if (kh == 0) {
                Al[0]  = make_float2(v1r[it], v1i[it]);
                Al[10] = make_float2(v2r[it], v2i[it]);
            } else {
                Al[kh]      = make_float2(v1r[it], v1i[it]);
                Al[20 - kh] = make_float2(v2r[it], v2i[it]);
            }
        }
    }
    __syncthreads();

    // ---- stage 2 (crop): items = 1440, <=3/thread ----
#pragma unroll
    for (int it = 0; it < 3; it++) {
        int o = tid + it * FFTTH;
        if (o < NJA * 180) {
            int r = o / 180, q = o - r * 180;
            int k2h = q / 20, k1 = q - k2h * 20;
            float y1r, y1i, y2r, y2i;
            dft20_conj(&A[r * LSTRV], k1, k2h, E20t, y1r, y1i, y2r, y2i);
            v1r[it] = y1r; v1i[it] = y1i;
            v2r[it] = y2r; v2i[it] = y2i;
        }
    }
    __syncthreads();
#pragma unroll
    for (int it = 0; it < 3; it++) {
        int o = tid + it * FFTTH;
        if (o < NJA * 180) {
            int r = o / 180, q = o - r * 180;
            int k2h = q / 20, k1 = q - k2h * 20;
            float2* Al = &A[r * LSTRV];
            if (k2h == 0) {
                Al[k1] = make_float2(v1r[it], v1i[it]);
            } else {
                if (k2h <= 7)
                    Al[20 * k2h + k1] = make_float2(v1r[it], v1i[it]);
                Al[320 - 20 * k2h + k1] = make_float2(v2r[it], v2i[it]);
            }
        }
    }
    __syncthreads();

    float2* At2 = (float2*)At;
    for (int o = tid; o < 320 * NJA; o += FFTTH) {
        int uc = o >> 3, r = o & 7;
        At2[((size_t)b * 320 + uc) * OS + j0 + r] = A[r * LSTRV + uc];
    }
}

// Pass B: lines = At rows (fixed uc), transform j axis; fused crop/shift/apod.
__global__ __launch_bounds__(FFTTH, 4)
void k_fft_pass_b(const float* __restrict__ At, float* __restrict__ out)
{
    __shared__ __align__(16) float2 A[NJB * LSTRV];
    __shared__ float2 E20t[20];
    __shared__ float2 E400p[424];
    __shared__ float apodT[320];
    int tid = threadIdx.x;
    int b = blockIdx.y;
    int uc0 = blockIdx.x * NJB;

    if (tid < 400) {
        float sn, cs;
        sincosf((float)tid * 0.015707963267948966f, &sn, &cs);
        E400p[tid + (tid >> 4)] = make_float2(cs, sn);
    } else if (tid >= 448 && tid < 468) {
        int t = tid - 448;
        float sn, cs;
        sincosf((float)t * 0.3141592653589793f, &sn, &cs);
        E20t[t] = make_float2(cs, sn);
    }
    if (tid < 320) apodT[tid] = apodf(tid);

    const float4* a4 = (const float4*)(At + ((size_t)b * 320 + uc0) * OS * 2);
    float4* A4 = (float4*)A;
    for (int o = tid; o < NJB * 200; o += FFTTH) {
        int r = o / 200, q = o - r * 200;
        A4[r * (LSTRV / 2) + q] = a4[o];
    }
    __syncthreads();

    float v1r[2], v1i[2], v2r[2], v2i[2];
#pragma unroll
    for (int it = 0; it < 2; it++) {
        int o = tid + it * FFTTH;
        if (o < NJB * 200) {
            int r = o / 200, q = o - r * 200;
            int kh = q / 20, n2 = q - kh * 20;
            float y1r, y1i, y2r, y2i;
            dft20_conj(&A[r * LSTRV], n2, kh, E20t, y1r, y1i, y2r, y2i);
            if (kh == 0) {
                v1r[it] = y1r; v1i[it] = y1i;
                int ti = 10 * n2;
                float2 tw = E400p[ti + (ti >> 4)];
                v2r[it] = y2r * tw.x - y2i * tw.y; v2i[it] = y2r * tw.y + y2i * tw.x;
            } else {
                int t1 = n2 * kh, t2 = n2 * (20 - kh);
                float2 w1 = E400p[t1 + (t1 >> 4)], w2 = E400p[t2 + (t2 >> 4)];
                v1r[it] = y1r * w1.x - y1i * w1.y; v1i[it] = y1r * w1.y + y1i * w1.x;
                v2r[it] = y2r * w2.x - y2i * w2.y; v2i[it] = y2r * w2.y + y2i * w2.x;
            }
        }
    }
    __syncthreads();
#pragma unroll
    for (int it = 0; it < 2; it++) {
        int o = tid + it * FFTTH;
        if (o < NJB * 200) {
            int r = o / 200, q = o - r * 200;
            int kh = q / 20, n2 = q - kh * 20;
            float2* Al = &A[r * LSTRV + 20 * n2];
            if (kh == 0) {
                Al[0]  = make_float2(v1r[it], v1i[it]);
                Al[10] = make_float2(v2r[it], v2i[it]);
            } else {
                Al[kh]      = make_float2(v1r[it], v1i[it]);
                Al[20 - kh] = make_float2(v2r[it], v2i[it]);
            }
        }
    }
    __syncthreads();

    for (int o = tid; o < NJB * 180; o += FFTTH) {
        int r = o / 180, q = o - r * 180;
        int k2h = q / 20, k1 = q - k2h * 20;
        float y1r, y1i, y2r, y2i;
        dft20_conj(&A[r * LSTRV], k1, k2h, E20t, y1r, y1i, y2r, y2i);

        int y = uc0 + r + 160; if (y >= 320) y -= 320;
        float apy = (1.0f / 320.0f) * apodT[y];
        float* o0 = out + (((size_t)b * 2 + 0) * NRES + y) * NRES;
        float* o1 = out + (((size_t)b * 2 + 1) * NRES + y) * NRES;

        if (k2h <= 7) {
            int vc = 20 * k2h + k1;
            int x = vc + 160; if (x >= 320) x -= 320;
            float sg = ((x + y) & 1) ? -1.0f : 1.0f;
            float sc = sg * apy * apodT[x];
            o0[x] = y1r * sc;
            o1[x] = y1i * sc;
        }
        if (k2h >= 1) {
            int vc = 320 - 20 * k2h + k1;
            int x = vc + 160; if (x >= 320) x -= 320;
            float sg = ((x + y) & 1) ? -1.0f : 1.0f;
            float sc = sg * apy * apodT[x];
            o0[x] = y2r * sc;
            o1[x] = y2i * sc;
        }
    }
}

extern "C" void kernel_launch(void* const* d_in, const int* in_sizes, int n_in,
                              void* d_out, int out_size, void* d_ws, size_t ws_size,
                              hipStream_t stream) {
    const float* ksp  = (const float*)d_in[0];
    const float* traj = (const float*)d_in[1];
    float* out = (float*)d_out;

    // ws layout (floats):
    //   grid    : NB*NCELL*2 = 5,120,000 (20.48 MB)
    //   At      : NB*320*OS*2 = 4,096,000 (16.38 MB)
    //   entries : CAP*NCELL float2 (20.48 MB)
    //   val     : NPTS*NB float2 (3.28 MB)
    //   kspT    : 320*320*NB float2 (13.1 MB)
    //   cursor  : NCELL ints; ovf_cnt; ovf
    float* grid = (float*)d_ws;
    float* At   = grid + (size_t)NB * NCELL * 2;
    float2* entries = (float2*)(At + (size_t)NB * 320 * OS * 2);
    float2* val  = (float2*)(entries + (size_t)CAP * NCELL);
    float2* kspT = val + (size_t)NPTS * NB;
    int* cursor  = (int*)(kspT + (size_t)NRES * NRES * NB);
    int* ovf_cnt = cursor + NCELL;
    OvfEntry* ovf = (OvfEntry*)(ovf_cnt + 16);

    k_transpose  <<<dim3(1600), 1024, 0, stream>>>((const float2*)ksp, kspT, cursor, ovf_cnt);
    k_sample_taps<<<dim3(1700), 256, 0, stream>>>(kspT, traj, val, cursor, entries, ovf_cnt, ovf);
    k_gather     <<<dim3((NCELL + 255) / 256), 256, 0, stream>>>(cursor, entries, (const float4*)val,
                                                                 (float2*)grid, ovf_cnt, ovf);
    k_fft_pass_a <<<dim3(OS / NJA, NB),  FFTTH, 0, stream>>>(grid, At);
    k_fft_pass_b <<<dim3(320 / NJB, NB), FFTTH, 0, stream>>>(At, out);
}

// Round 13
// 147.230 us; speedup vs baseline: 1.0266x; 1.0009x over previous
//
#include <hip/hip_runtime.h>
#include <hip/hip_fp16.h>

#define NPTS   25600
#define NB     16
#define NRES   320
#define OS     400
#define NCELL  (OS * OS)      // 160000
#define CAP    16
#define MAXOVF 4096

#define NJA    8              // lines per pass-A block
#define NJB    5              // lines per pass-B block
#define FFTTH  512            // threads per FFT block
#define LSTRV  404            // LDS line stride in float2

// BETA = pi * sqrt((4/1.25*0.75)^2 - 0.8) = pi*sqrt(4.96)
#define BETA_F (3.14159265358979f * 2.22710574513201f)

struct H2X2 { __half2 a, b; };   // two packed complex-fp16 cells (8 B)

__device__ __forceinline__ float bessel_i0f(float x) {
    float ax = fabsf(x);
    if (ax < 3.75f) {
        float t = (ax * ax) * (1.0f / 14.0625f);
        return 1.0f + t * (3.5156229f + t * (3.0899424f + t * (1.2067492f +
                     t * (0.2659732f + t * (0.0360768f + t * 0.0045813f)))));
    } else {
        float t = 3.75f / ax;
        return (expf(ax) * rsqrtf(ax)) *
               (0.39894228f + t * (0.01328592f + t * (0.00225319f + t * (-0.00157565f +
                t * (0.00916281f + t * (-0.02057706f + t * (0.02635537f +
                t * (-0.01647633f + t * 0.00392377f))))))));
    }
}

struct OvfEntry { int cell; int m; float w; float pad; };

// ---------------------------------------------------------------------------
// Transpose ksp (b,y,x) -> kspT (y,x,b); zeroes cursor/ovf_cnt.
// ---------------------------------------------------------------------------
__global__ __launch_bounds__(1024)
void k_transpose(const float2* __restrict__ ksp, float2* __restrict__ kspT,
                 int* __restrict__ cursor, int* __restrict__ ovf_cnt)
{
    __shared__ float2 T[8 * 8 * 17];
    int tid = threadIdx.x;
    int bx = blockIdx.x % 40, by = blockIdx.x / 40;
    int x0 = bx * 8, y0 = by * 8;

    int cbase = blockIdx.x * 100;
    if (tid < 100) cursor[cbase + tid] = 0;
    if (blockIdx.x == 0 && tid >= 100 && tid < 116) ovf_cnt[tid - 100] = 0;

    int b  = tid >> 6, yl = (tid >> 3) & 7, xl = tid & 7;
    T[(yl * 8 + xl) * 17 + b] = ksp[((size_t)b * NRES + (y0 + yl)) * NRES + x0 + xl];
    __syncthreads();

    int yl2 = tid >> 7, xl2 = (tid >> 4) & 7, b2 = tid & 15;
    kspT[((size_t)(y0 + yl2) * NRES + x0 + xl2) * NB + b2] = T[(yl2 * 8 + xl2) * 17 + b2];
}

// ---------------------------------------------------------------------------
// Fused sample (coalesced kspT rows) + KB taps. NOTE: w0 carries the final
// 1/320 output scale (linear pipeline) so fp16 intermediates stay small.
// ---------------------------------------------------------------------------
__global__ __launch_bounds__(256)
void k_sample_taps(const float2* __restrict__ kspT,
                   const float* __restrict__ traj,
                   float2* __restrict__ val,
                   int* __restrict__ cursor,
                   float2* __restrict__ entries,
                   int* __restrict__ ovf_cnt,
                   OvfEntry* __restrict__ ovf)
{
    int blk = blockIdx.x;
    if (blk < 1600) {
        int gid = blk * 256 + threadIdx.x;
        int b = gid & 15;
        int m = gid >> 4;

        float tx = traj[2 * m + 0];
        float ty = traj[2 * m + 1];

        float px = (tx * (1.0f / 160.0f) + 1.0f) * 0.5f * 319.0f;
        float py = (ty * (1.0f / 160.0f) + 1.0f) * 0.5f * 319.0f;
        float fx0 = floorf(px), fy0 = floorf(py);
        int x0 = (int)fx0, y0 = (int)fy0;
        float wx1 = px - fx0, wy1 = py - fy0;
        float wx0 = 1.0f - wx1, wy0 = 1.0f - wy1;

        const float2* row0 = kspT + ((size_t)y0 * NRES + x0) * NB + b;
        const float2* row1 = row0 + (size_t)NRES * NB;
        float2 v00 = row0[0];
        float2 v01 = row0[NB];
        float2 v10 = row1[0];
        float2 v11 = row1[NB];
        float sr = (v00.x * wx0 + v01.x * wx1) * wy0 + (v10.x * wx0 + v11.x * wx1) * wy1;
        float si = (v00.y * wx0 + v01.y * wx1) * wy0 + (v10.y * wx0 + v11.y * wx1) * wy1;

        val[gid] = make_float2(sr, si);
    } else {
        int m = (blk - 1600) * 256 + threadIdx.x;
        if (m >= NPTS) return;

        float tx = traj[2 * m + 0];
        float ty = traj[2 * m + 1];
        float c0 = tx * 1.25f + 200.0f;
        float c1 = ty * 1.25f + 200.0f;
        float s0 = ceilf(c0 - 2.0f);
        float s1 = ceilf(c1 - 2.0f);

        float w0[4], w1[4];
        int   i0[4], i1[4];
#pragma unroll
        for (int t = 0; t < 4; t++) {
            float id0 = s0 + (float)t;
            float d0 = (c0 - id0) * 0.5f;
            float t0 = fmaxf(1.0f - d0 * d0, 0.0f);
            w0[t] = bessel_i0f(BETA_F * sqrtf(t0)) * (0.25f / 320.0f);  // folded 1/320
            i0[t] = (((int)id0) + OS) % OS;

            float id1 = s1 + (float)t;
            float d1 = (c1 - id1) * 0.5f;
            float t1 = fmaxf(1.0f - d1 * d1, 0.0f);
            w1[t] = bessel_i0f(BETA_F * sqrtf(t1)) * 0.25f;
            i1[t] = (((int)id1) + OS) % OS;
        }

#pragma unroll
        for (int t0 = 0; t0 < 4; t0++) {
#pragma unroll
            for (int t1 = 0; t1 < 4; t1++) {
                int cell = i1[t1] * OS + i0[t0];
                float w = w0[t0] * w1[t1];
                int slot = atomicAdd(&cursor[cell], 1);
                if (slot < CAP) {
                    entries[(size_t)slot * NCELL + cell] = make_float2(__int_as_float(m), w);
                } else {
                    int oi = atomicAdd(ovf_cnt, 1);
                    if (oi < MAXOVF) { ovf[oi].cell = cell; ovf[oi].m = m; ovf[oi].w = w; }
                }
            }
        }
    }
}

// ---------------------------------------------------------------------------
// Gather-SpMM -> fp16 grid (half2 per complex), halving the grid round trip.
// ---------------------------------------------------------------------------
__global__ __launch_bounds__(256)
void k_gather(const int* __restrict__ cursor,
              const float2* __restrict__ entries,
              const float4* __restrict__ val4,   // (25600, 8 float4)
              __half2* __restrict__ grid,
              const int* __restrict__ ovf_cnt,
              const OvfEntry* __restrict__ ovf)
{
    int cell = blockIdx.x * blockDim.x + threadIdx.x;
    if (cell >= NCELL) return;
    int cnt_raw = cursor[cell];
    int cnt = min(cnt_raw, CAP);

    float4 acc[8];
#pragma unroll
    for (int q = 0; q < 8; q++) acc[q] = make_float4(0.f, 0.f, 0.f, 0.f);

    for (int k = 0; k < cnt; k++) {
        float2 e = entries[(size_t)k * NCELL + cell];
        int m = __float_as_int(e.x);
        float w = e.y;
        const float4* v = val4 + (size_t)m * 8;
#pragma unroll
        for (int q = 0; q < 8; q++) {
            float4 x = v[q];
            acc[q].x = fmaf(w, x.x, acc[q].x);
            acc[q].y = fmaf(w, x.y, acc[q].y);
            acc[q].z = fmaf(w, x.z, acc[q].z);
            acc[q].w = fmaf(w, x.w, acc[q].w);
        }
    }

    if (cnt_raw > CAP) {
        int n = min(*ovf_cnt, MAXOVF);
        for (int i = 0; i < n; i++) {
            if (ovf[i].cell != cell) continue;
            int m = ovf[i].m;
            float w = ovf[i].w;
            const float4* v = val4 + (size_t)m * 8;
#pragma unroll
            for (int q = 0; q < 8; q++) {
                float4 x = v[q];
                acc[q].x = fmaf(w, x.x, acc[q].x);
                acc[q].y = fmaf(w, x.y, acc[q].y);
                acc[q].z = fmaf(w, x.z, acc[q].z);
                acc[q].w = fmaf(w, x.w, acc[q].w);
            }
        }
    }

#pragma unroll
    for (int q = 0; q < 8; q++) {
        grid[(size_t)(2 * q + 0) * NCELL + cell] = __float22half2_rn(make_float2(acc[q].x, acc[q].y));
        grid[(size_t)(2 * q + 1) * NCELL + cell] = __float22half2_rn(make_float2(acc[q].z, acc[q].w));
    }
}

// ---------------------------------------------------------------------------
// 20-pt conjugate-pair sub-DFT with pairing folded in (fp32 in LDS/regs).
// ---------------------------------------------------------------------------
__device__ __forceinline__ void dft20_conj(const float2* __restrict__ Al, int off, int kh,
                                           const float2* __restrict__ E20t,
                                           float& y1r, float& y1i, float& y2r, float& y2i)
{
    float2 x0 = Al[off], x10 = Al[off + 200];
    if (kh == 0) {
        float br = x0.x + x10.x, bi = x0.y + x10.y;
        float ar = 0.f, ai = 0.f, dr = 0.f, di = 0.f;
#pragma unroll
        for (int j = 1; j <= 9; j++) {
            float2 xa = Al[off + 20 * j];
            float2 xb = Al[off + 400 - 20 * j];
            float pr = xa.x + xb.x, pi = xa.y + xb.y;
            ar += pr; ai += pi;
            float sg = (j & 1) ? -1.f : 1.f;
            dr = fmaf(sg, pr, dr); di = fmaf(sg, pi, di);
        }
        y1r = br + ar; y1i = bi + ai;     // k = 0
        y2r = br + dr; y2i = bi + di;     // k = 10
    } else {
        float sgn = (kh & 1) ? -1.f : 1.f;
        float br = fmaf(sgn, x10.x, x0.x), bi = fmaf(sgn, x10.y, x0.y);
        float2 ek = E20t[kh];
        float c = ek.x, s = ek.y;
        float Asr = 0.f, Asi = 0.f, Bsr = 0.f, Bsi = 0.f;
#pragma unroll
        for (int j = 1; j <= 9; j++) {
            float2 xa = Al[off + 20 * j];
            float2 xb = Al[off + 400 - 20 * j];
            float pr = xa.x + xb.x, pi = xa.y + xb.y;   // xp
            float mr = xa.x - xb.x, mi = xa.y - xb.y;   // xm
            Asr = fmaf(c, pr, Asr); Asi = fmaf(c, pi, Asi);
            Bsr = fmaf(s, mi, Bsr); Bsi = fmaf(s, mr, Bsi);
            float cn = c * ek.x - s * ek.y;
            s = c * ek.y + s * ek.x;
            c = cn;
        }
        y1r = br + Asr - Bsr; y1i = bi + Asi + Bsi;     // k = kh
        y2r = br + Asr + Bsr; y2i = bi + Asi - Bsi;     // k = 20-kh
    }
}

__device__ __forceinline__ float apodf(int i) {
    float t = (float)(i - 160) * 0.031415926535897932f;  // pi*4/400
    float a = sqrtf(fmaxf(BETA_F * BETA_F - t * t, 1e-12f));
    return a / sinhf(a);
}

// Pass A: fp16 grid lines -> fp32 LDS DFT -> fp16 At[b][uc][j].
__global__ __launch_bounds__(FFTTH, 4)
void k_fft_pass_a(const __half2* __restrict__ grid, __half2* __restrict__ At)
{
    __shared__ __align__(16) float2 A[NJA * LSTRV];
    __shared__ float2 E20t[20];
    __shared__ float2 E400p[424];     // swizzled: entry t at t + (t>>4)
    int tid = threadIdx.x;
    int b = blockIdx.y;
    int j0 = blockIdx.x * NJA;

    if (tid < 400) {
        float sn, cs;
        sincosf((float)tid * 0.015707963267948966f, &sn, &cs);   // 2*pi/400
        E400p[tid + (tid >> 4)] = make_float2(cs, sn);
    } else if (tid >= 448 && tid < 468) {
        int t = tid - 448;
        float sn, cs;
        sincosf((float)t * 0.3141592653589793f, &sn, &cs);       // 2*pi/20
        E20t[t] = make_float2(cs, sn);
    }

    const H2X2* g2 = (const H2X2*)(grid + (size_t)b * NCELL + (size_t)j0 * OS);
    for (int o = tid; o < NJA * 200; o += FFTTH) {
        int r = o / 200, q = o - r * 200;
        H2X2 v = g2[o];
        A[r * LSTRV + 2 * q]     = __half22float2(v.a);
        A[r * LSTRV + 2 * q + 1] = __half22float2(v.b);
    }
    __syncthreads();

    // ---- stage 1: items = 1600, <=4/thread, reg-held ----
    float v1r[4], v1i[4], v2r[4], v2i[4];
#pragma unroll
    for (int it = 0; it < 4; it++) {
        int o = tid + it * FFTTH;
        if (o < NJA * 200) {
            int r = o / 200, q = o - r * 200;
            int kh = q / 20, n2 = q - kh * 20;
            float y1r, y1i, y2r, y2i;
            dft20_conj(&A[r * LSTRV], n2, kh, E20t, y1r, y1i, y2r, y2i);
            if (kh == 0) {
                v1r[it] = y1r; v1i[it] = y1i;
                int ti = 10 * n2;
                float2 tw = E400p[ti + (ti >> 4)];
                v2r[it] = y2r * tw.x - y2i * tw.y; v2i[it] = y2r * tw.y + y2i * tw.x;
            } else {
                int t1 = n2 * kh, t2 = n2 * (20 - kh);
                float2 w1 = E400p[t1 + (t1 >> 4)], w2 = E400p[t2 + (t2 >> 4)];
                v1r[it] = y1r * w1.x - y1i * w1.y; v1i[it] = y1r * w1.y + y1i * w1.x;
                v2r[it] = y2r * w2.x - y2i * w2.y; v2i[it] = y2r * w2.y + y2i * w2.x;
            }
        }
    }
    __syncthreads();
#pragma unroll
    for (int it = 0; it < 4; it++) {
        int o = tid + it * FFTTH;
        if (o < NJA * 200) {
            int r = o / 200, q = o - r * 200;
            int kh = q / 20, n2 = q - kh * 20;
            float2* Al = &A[r * LSTRV + 20 * n2];
            if (kh == 0) {
                Al[0]  = make_float2(v1r[it], v1i[it]);
                Al[10] = make_float2(v2r[it], v2i[it]);
            } else {
                Al[kh]      = make_float2(v1r[it], v1i[it]);
                Al[20 - kh] = make_float2(v2r[it], v2i[it]);
            }
        }
    }
    __syncthreads();

    // ---- stage 2 (crop): items = 1440, <=3/thread ----
#pragma unroll
    for (int it = 0; it < 3; it++) {
        int o = tid + it * FFTTH;
        if (o < NJA * 180) {
            int r = o / 180, q = o - r * 180;
            int k2h = q / 20, k1 = q - k2h * 20;
            float y1r, y1i, y2r, y2i;
            dft20_conj(&A[r * LSTRV], k1, k2h, E20t, y1r, y1i, y2r, y2i);
            v1r[it] = y1r; v1i[it] = y1i;
            v2r[it] = y2r; v2i[it] = y2i;
        }
    }
    __syncthreads();
#pragma unroll
    for (int it = 0; it < 3; it++) {
        int o = tid + it * FFTTH;
        if (o < NJA * 180) {
            int r = o / 180, q = o - r * 180;
            int k2h = q / 20, k1 = q - k2h * 20;
            float2* Al = &A[r * LSTRV];
            if (k2h == 0) {
                Al[k1] = make_float2(v1r[it], v1i[it]);
            } else {
                if (k2h <= 7)
                    Al[20 * k2h + k1] = make_float2(v1r[it], v1i[it]);
                Al[320 - 20 * k2h + k1] = make_float2(v2r[it], v2i[it]);
            }
        }
    }
    __syncthreads();

    for (int o = tid; o < 320 * NJA; o += FFTTH) {
        int uc = o >> 3, r = o & 7;
        At[((size_t)b * 320 + uc) * OS + j0 + r] = __float22half2_rn(A[r * LSTRV + uc]);
    }
}

// Pass B: fp16 At lines -> fp32 DFT -> fused crop/shift/apod epilogue.
__global__ __launch_bounds__(FFTTH, 4)
void k_fft_pass_b(const __half2* __restrict__ At, float* __restrict__ out)
{
    __shared__ __align__(16) float2 A[NJB * LSTRV];
    __shared__ float2 E20t[20];
    __shared__ float2 E400p[424];
    __shared__ float apodT[320];
    int tid = threadIdx.x;
    int b = blockIdx.y;
    int uc0 = blockIdx.x * NJB;

    if (tid < 400) {
        float sn, cs;
        sincosf((float)tid * 0.015707963267948966f, &sn, &cs);
        E400p[tid + (tid >> 4)] = make_float2(cs, sn);
    } else if (tid >= 448 && tid < 468) {
        int t = tid - 448;
        float sn, cs;
        sincosf((float)t * 0.3141592653589793f, &sn, &cs);
        E20t[t] = make_float2(cs, sn);
    }
    if (tid < 320) apodT[tid] = apodf(tid);

    const H2X2* a2 = (const H2X2*)(At + ((size_t)b * 320 + uc0) * OS);
    for (int o = tid; o < NJB * 200; o += FFTTH) {
        int r = o / 200, q = o - r * 200;
        H2X2 v = a2[o];
        A[r * LSTRV + 2 * q]     = __half22float2(v.a);
        A[r * LSTRV + 2 * q + 1] = __half22float2(v.b);
    }
    __syncthreads();

    float v1r[2], v1i[2], v2r[2], v2i[2];
#pragma unroll
    for (int it = 0; it < 2; it++) {
        int o = tid + it * FFTTH;
        if (o < NJB * 200) {
            int r = o / 200, q = o - r * 200;
            int kh = q / 20, n2 = q - kh * 20;
            float y1r, y1i, y2r, y2i;
            dft20_conj(&A[r * LSTRV], n2, kh, E20t, y1r, y1i, y2r, y2i);
            if (kh == 0) {
                v1r[it] = y1r; v1i[it] = y1i;
                int ti = 10 * n2;
                float2 tw = E400p[ti + (ti >> 4)];
                v2r[it] = y2r * tw.x - y2i * tw.y; v2i[it] = y2r * tw.y + y2i * tw.x;
            } else {
                int t1 = n2 * kh, t2 = n2 * (20 - kh);
                float2 w1 = E400p[t1 + (t1 >> 4)], w2 = E400p[t2 + (t2 >> 4)];
                v1r[it] = y1r * w1.x - y1i * w1.y; v1i[it] = y1r * w1.y + y1i * w1.x;
                v2r[it] = y2r * w2.x - y2i * w2.y; v2i[it] = y2r * w2.y + y2i * w2.x;
            }
        }
    }
    __syncthreads();
#pragma unroll
    for (int it = 0; it < 2; it++) {
        int o = tid + it * FFTTH;
        if (o < NJB * 200) {
            int r = o / 200, q = o - r * 200;
            int kh = q / 20, n2 = q - kh * 20;
            float2* Al = &A[r * LSTRV + 20 * n2];
            if (kh == 0) {
                Al[0]  = make_float2(v1r[it], v1i[it]);
                Al[10] = make_float2(v2r[it], v2i[it]);
            } else {
                Al[kh]      = make_float2(v1r[it], v1i[it]);
                Al[20 - kh] = make_float2(v2r[it], v2i[it]);
            }
        }
    }
    __syncthreads();

    for (int o = tid; o < NJB * 180; o += FFTTH) {
        int r = o / 180, q = o - r * 180;
        int k2h = q / 20, k1 = q - k2h * 20;
        float y1r, y1i, y2r, y2i;
        dft20_conj(&A[r * LSTRV], k1, k2h, E20t, y1r, y1i, y2r, y2i);

        int y = uc0 + r + 160; if (y >= 320) y -= 320;
        float apy = apodT[y];                    // 1/320 already folded into w0
        float* o0 = out + (((size_t)b * 2 + 0) * NRES + y) * NRES;
        float* o1 = out + (((size_t)b * 2 + 1) * NRES + y) * NRES;

        if (k2h <= 7) {
            int vc = 20 * k2h + k1;
            int x = vc + 160; if (x >= 320) x -= 320;
            float sg = ((x + y) & 1) ? -1.0f : 1.0f;
            float sc = sg * apy * apodT[x];
            o0[x] = y1r * sc;
            o1[x] = y1i * sc;
        }
        if (k2h >= 1) {
            int vc = 320 - 20 * k2h + k1;
            int x = vc + 160; if (x >= 320) x -= 320;
            float sg = ((x + y) & 1) ? -1.0f : 1.0f;
            float sc = sg * apy * apodT[x];
            o0[x] = y2r * sc;
            o1[x] = y2i * sc;
        }
    }
}

extern "C" void kernel_launch(void* const* d_in, const int* in_sizes, int n_in,
                              void* d_out, int out_size, void* d_ws, size_t ws_size,
                              hipStream_t stream) {
    const float* ksp  = (const float*)d_in[0];
    const float* traj = (const float*)d_in[1];
    float* out = (float*)d_out;

    // ws layout (floats):
    //   grid_h  : NB*NCELL half2   = 2,560,000 floats-worth (10.24 MB)
    //   At_h    : NB*320*OS half2  = 2,048,000 floats-worth ( 8.19 MB)
    //   entries : CAP*NCELL float2 (20.48 MB)
    //   val     : NPTS*NB float2 (3.28 MB)
    //   kspT    : 320*320*NB float2 (13.1 MB)
    //   cursor  : NCELL ints; ovf_cnt; ovf
    float* base = (float*)d_ws;
    __half2* grid_h = (__half2*)base;
    __half2* At_h   = (__half2*)(base + (size_t)NB * NCELL);          // grid_h = NB*NCELL half2 = NB*NCELL floats
    float2* entries = (float2*)(base + (size_t)NB * NCELL + (size_t)NB * 320 * OS);
    float2* val  = entries + (size_t)CAP * NCELL;
    float2* kspT = val + (size_t)NPTS * NB;
    int* cursor  = (int*)(kspT + (size_t)NRES * NRES * NB);
    int* ovf_cnt = cursor + NCELL;
    OvfEntry* ovf = (OvfEntry*)(ovf_cnt + 16);

    k_transpose  <<<dim3(1600), 1024, 0, stream>>>((const float2*)ksp, kspT, cursor, ovf_cnt);
    k_sample_taps<<<dim3(1700), 256, 0, stream>>>(kspT, traj, val, cursor, entries, ovf_cnt, ovf);
    k_gather     <<<dim3((NCELL + 255) / 256), 256, 0, stream>>>(cursor, entries, (const float4*)val,
                                                                 grid_h, ovf_cnt, ovf);
    k_fft_pass_a <<<dim3(OS / NJA, NB),  FFTTH, 0, stream>>>(grid_h, At_h);
    k_fft_pass_b <<<dim3(320 / NJB, NB), FFTTH, 0, stream>>>(At_h, out);
}